// Round 6
// baseline (1531.854 us; speedup 1.0000x reference)
//
#include <hip/hip_runtime.h>
#include <float.h>

#define B_  32
#define C_  3
#define H_  64
#define W_  64
#define N_  2048
#define D_  128
#define KNN 8
#define PS  75        // 3*5*5
#define QP  8         // distances per top-k batch check

// ---------------------------------------------------------------------------
// Kernel 1: bias[n] = 0.5 * ||patches[n]||^2
// ---------------------------------------------------------------------------
__global__ __launch_bounds__(256) void bias_kernel(const float* __restrict__ patches,
                                                   float* __restrict__ bias) {
  int n = blockIdx.x * 256 + threadIdx.x;
  if (n < N_) {
    const float* __restrict__ p = patches + n * PS;
    float s = 0.f;
#pragma unroll
    for (int j = 0; j < PS; j++) s += p[j] * p[j];
    bias[n] = 0.5f * s;
  }
}

// streaming top-8 insert, fully unrolled, register-resident arrays
// (round-3 counters prove these 8-element arrays SROA to registers fine)
__device__ __forceinline__ void insert8(float d, int idx, float td[KNN], int ti[KNN],
                                        float& tmax, int& tslot) {
  if (d < tmax) {
#pragma unroll
    for (int s = 0; s < KNN; s++) if (s == tslot) { td[s] = d; ti[s] = idx; }
    float m = td[0]; int ms = 0;
#pragma unroll
    for (int s = 1; s < KNN; s++) if (td[s] > m) { m = td[s]; ms = s; }
    tmax = m; tslot = ms;
  }
}

// ---------------------------------------------------------------------------
// The x-patch as 75 NAMED SCALARS (X-macro generated). Rounds 1-5 proved the
// backend demotes a float xv[75] array to scratch no matter what occupancy
// hints it gets (VGPR_Count pinned at 52-68 across launch_bounds /
// waves_per_eu / LDS-governor attempts); named SSA values give it nothing to
// demote. Grid is sized for 2 waves/SIMD so the 256-VGPR budget is legal.
// ---------------------------------------------------------------------------
#define XV_LIST(M) \
  M(0) M(1) M(2) M(3) M(4) M(5) M(6) M(7) M(8) M(9) \
  M(10) M(11) M(12) M(13) M(14) M(15) M(16) M(17) M(18) M(19) \
  M(20) M(21) M(22) M(23) M(24) M(25) M(26) M(27) M(28) M(29) \
  M(30) M(31) M(32) M(33) M(34) M(35) M(36) M(37) M(38) M(39) \
  M(40) M(41) M(42) M(43) M(44) M(45) M(46) M(47) M(48) M(49) \
  M(50) M(51) M(52) M(53) M(54) M(55) M(56) M(57) M(58) M(59) \
  M(60) M(61) M(62) M(63) M(64) M(65) M(66) M(67) M(68) M(69) \
  M(70) M(71) M(72) M(73) M(74)

#define XV_DECL(J) float xv##J;
#define XV_LOAD(J) { \
    constexpr int cc = (J) / 25, dh = ((J) / 5) % 5, dw = (J) % 5; \
    const int hh = h + dh - 2, ww = w + dw - 2; \
    xv##J = ((unsigned)hh < 64u && (unsigned)ww < 64u) \
              ? x[((b * C_ + cc) * H_ + hh) * W_ + ww] : 0.f; }

// one even/odd step for two patches: 4 independent FMA chains (a0,b0,a1,b1)
#define P2(JA, JB) \
  a0 = fmaf(p0[JA], xv##JA, a0); b0 = fmaf(p0[JB], xv##JB, b0); \
  a1 = fmaf(p1[JA], xv##JA, a1); b1 = fmaf(p1[JB], xv##JB, b1);

#define DOT_BODY \
  P2(0,1)   P2(2,3)   P2(4,5)   P2(6,7)   P2(8,9) \
  P2(10,11) P2(12,13) P2(14,15) P2(16,17) P2(18,19) \
  P2(20,21) P2(22,23) P2(24,25) P2(26,27) P2(28,29) \
  P2(30,31) P2(32,33) P2(34,35) P2(36,37) P2(38,39) \
  P2(40,41) P2(42,43) P2(44,45) P2(46,47) P2(48,49) \
  P2(50,51) P2(52,53) P2(54,55) P2(56,57) P2(58,59) \
  P2(60,61) P2(62,63) P2(64,65) P2(66,67) P2(68,69) \
  P2(70,71) P2(72,73) \
  a0 = fmaf(p0[74], xv74, a0); a1 = fmaf(p1[74], xv74, a1);

// ---------------------------------------------------------------------------
// Kernel 2: 512 blocks x 4 waves; each wave owns 64 pixels and scans the FULL
// 2048-patch dictionary (no split -> no merge, no LDS). 2 waves/SIMD ->
// 256-VGPR budget; live set ~140 so nothing spills. Patch rows are
// wave-uniform -> scalar-pipe s_loads (free SGPR operand in v_fma).
// ---------------------------------------------------------------------------
__global__ __launch_bounds__(256, 2)
void topk_kernel(const float* __restrict__ x, const float* __restrict__ patches,
                 const float* __restrict__ values, const float* __restrict__ bias,
                 float* __restrict__ out) {
  const int pix = blockIdx.x * 256 + threadIdx.x;
  const int w = pix & 63;
  const int h = (pix >> 6) & 63;
  const int b = pix >> 12;

  XV_LIST(XV_DECL)
  XV_LIST(XV_LOAD)

  float td[KNN];
  int ti[KNN];
#pragma unroll
  for (int s = 0; s < KNN; s++) { td[s] = FLT_MAX; ti[s] = 0; }
  float tmax = FLT_MAX;
  int tslot = 0;

#pragma unroll 1
  for (int n = 0; n < N_; n += QP) {
    float d[QP];
#pragma unroll
    for (int qq = 0; qq < QP; qq += 2) {
      const float* __restrict__ p0 = patches + (n + qq) * PS;  // uniform base
      const float* __restrict__ p1 = p0 + PS;
      float a0 = 0.f, a1 = 0.f, b0 = 0.f, b1 = 0.f;
      DOT_BODY
      d[qq]     = bias[n + qq]     - (a0 + b0);
      d[qq + 1] = bias[n + qq + 1] - (a1 + b1);
    }
    float m = d[0];
#pragma unroll
    for (int q = 1; q < QP; q++) m = fminf(m, d[q]);
    if (m < tmax) {
#pragma unroll
      for (int q = 0; q < QP; q++) insert8(d[q], n + q, td, ti, tmax, tslot);
    }
  }

  // ---- epilogue: per-lane gather + mean; lane = w -> coalesced stores ----
  int base[KNN];
#pragma unroll
  for (int s = 0; s < KNN; s++) base[s] = ti[s] * D_;
  const int obase = b * (D_ * H_ * W_) + h * W_ + w;
#pragma unroll 1
  for (int dd = 0; dd < D_; dd += 4) {
    float s0 = 0.f, s1 = 0.f, s2 = 0.f, s3 = 0.f;
#pragma unroll
    for (int k = 0; k < KNN; k++) {
      const float4 v = *(const float4*)(values + base[k] + dd);
      s0 += v.x; s1 += v.y; s2 += v.z; s3 += v.w;
    }
    out[obase + (dd + 0) * (H_ * W_)] = s0 * 0.125f;
    out[obase + (dd + 1) * (H_ * W_)] = s1 * 0.125f;
    out[obase + (dd + 2) * (H_ * W_)] = s2 * 0.125f;
    out[obase + (dd + 3) * (H_ * W_)] = s3 * 0.125f;
  }
}

// ---------------------------------------------------------------------------
extern "C" void kernel_launch(void* const* d_in, const int* in_sizes, int n_in,
                              void* d_out, int out_size, void* d_ws, size_t ws_size,
                              hipStream_t stream) {
  const float* x = (const float*)d_in[0];
  const float* patches = (const float*)d_in[1];
  const float* values = (const float*)d_in[2];
  float* out = (float*)d_out;
  float* bias = (float*)d_ws;  // 2048 floats of scratch

  hipLaunchKernelGGL(bias_kernel, dim3(N_ / 256), dim3(256), 0, stream, patches, bias);
  hipLaunchKernelGGL(topk_kernel, dim3((B_ * H_ * W_) / 256), dim3(256), 0, stream,
                     x, patches, values, bias, out);
}